// Round 6
// baseline (25398.055 us; speedup 1.0000x reference)
//
#include <hip/hip_runtime.h>
#include <stdint.h>

typedef unsigned int u32;
typedef unsigned long long u64;

#define NBLK 256
#define NTHR 1024
#define Bz 4
#define Tz 128
#define Hz 1024
#define Ez 512
#define Az 512
#define Vz 16000
#define NSTEPS 512
#define XS 1032   // LDS row stride (floats); 1032*4 bytes is 16B-aligned, 8-bank shift/row

// ---------------- ws layout (bytes) ----------------
// [0,      16384)  ctrl u32s: grp[g] @ g*16 (g<16), root @ 256, gen @ 320, avflag @ 384
// [16384,  49152)  h_g[2][4][1024] f32  (double-buffered)
// [49152,  57344)  av_g[4][512] f32
// [57344,  65536)  amax_g[256][4] u64
// [65536,  3211264)   encout[4][128][1024] f32 (2MB) then pt[4][512][128] f32 (1MB)
// [3211264, 3735552)  scorepart[4][128][256] f32 (512KB)
// [3735552, 5832704)  qhpart[4][512][256] f32 (2MB)

__device__ __forceinline__ float sigf(float x) { return 1.0f / (1.0f + expf(-x)); }

// interleaved k-split dot: lane owns float4 chunks {lane + L*k : k<K}
template <int K, int L>
__device__ __forceinline__ float idot(const float4* __restrict__ w4,
                                      const float4* __restrict__ v4, int lane) {
  float4 acc = make_float4(0.f, 0.f, 0.f, 0.f);
#pragma unroll 8
  for (int k = 0; k < K; ++k) {
    float4 a = w4[lane + L * k];
    float4 b = v4[lane + L * k];
    acc.x += a.x * b.x; acc.y += a.y * b.y; acc.z += a.z * b.z; acc.w += a.w * b.w;
  }
  return (acc.x + acc.y) + (acc.z + acc.w);
}

// interleaved k-split SUM: lane owns float4 chunks {lane + L*k : k<K}
template <int K, int L>
__device__ __forceinline__ float isum(const float* __restrict__ p, int lane) {
  const float4* p4 = (const float4*)p;
  float4 acc = make_float4(0.f, 0.f, 0.f, 0.f);
#pragma unroll
  for (int k = 0; k < K; ++k) {
    float4 v = p4[lane + L * k];
    acc.x += v.x; acc.y += v.y; acc.z += v.z; acc.w += v.w;
  }
  return (acc.x + acc.y) + (acc.z + acc.w);
}

// two-level grid barrier, monotonic epochs; arrive/wait split so non-consumer
// blocks can skip the poll. Polls RELAXED + one ACQUIRE on exit.
__device__ __forceinline__ void bar_arrive(u32* ctrl, int epoch) {
  __syncthreads();  // drains this block's stores before release
  if (threadIdx.x == 0) {
    const u32 target = (u32)epoch * 16u;
    u32* grp = ctrl + ((blockIdx.x >> 4) * 16);
    u32 v = __hip_atomic_fetch_add(grp, 1u, __ATOMIC_RELEASE, __HIP_MEMORY_SCOPE_AGENT);
    if (v == target - 1u) {
      u32 r = __hip_atomic_fetch_add(ctrl + 256, 1u, __ATOMIC_ACQ_REL, __HIP_MEMORY_SCOPE_AGENT);
      if (r == target - 1u)
        __hip_atomic_store(ctrl + 320, (u32)epoch, __ATOMIC_RELEASE, __HIP_MEMORY_SCOPE_AGENT);
    }
  }
}

__device__ __forceinline__ void bar_wait(u32* ctrl, int epoch) {
  if (threadIdx.x == 0) {
    while (__hip_atomic_load(ctrl + 320, __ATOMIC_RELAXED, __HIP_MEMORY_SCOPE_AGENT) < (u32)epoch)
      __builtin_amdgcn_s_sleep(4);
    (void)__hip_atomic_load(ctrl + 320, __ATOMIC_ACQUIRE, __HIP_MEMORY_SCOPE_AGENT);
  }
  __syncthreads();
}

__global__ void __launch_bounds__(NTHR, 1) seq2seq_kernel(
    const int* __restrict__ inputs,
    const float* __restrict__ enc_emb, const float* __restrict__ enc_Wih,
    const float* __restrict__ enc_Whh, const float* __restrict__ enc_bih,
    const float* __restrict__ enc_bhh,
    const float* __restrict__ dec_emb, const float* __restrict__ dec_Wih,
    const float* __restrict__ dec_Whh, const float* __restrict__ dec_bih,
    const float* __restrict__ dec_bhh,
    const float* __restrict__ W_av, const float* __restrict__ b_av,
    const float* __restrict__ W_cls, const float* __restrict__ b_cls,
    float* __restrict__ out, char* __restrict__ ws) {
  const int tid = threadIdx.x;
  const int bid = blockIdx.x;

  u32* ctrl = (u32*)ws;
  float* h_g = (float*)(ws + 16384);     // [2][4][1024]
  float* av_g = (float*)(ws + 49152);    // [4][512]
  u64* amax_g = (u64*)(ws + 57344);      // [256][4]
  float* encout_g = (float*)(ws + 65536);
  float* pt_g = encout_g + Bz * Tz * Hz;
  float* scorepart_g = pt_g + Bz * Az * Tz;    // [4][128][256]
  float* qhpart_g = scorepart_g + Bz * Tz * 256; // [4][512][256]
  float* out_pred = out;                        // [512][4][16000]
  float* out_aw = out + (long)NSTEPS * Bz * Vz; // [512][4][128]

  // GRU weights LDS-resident: rows 0..11 = W_ih, 12..23 = W_hh. ~96.75 KB.
  __shared__ __align__(16) float wlds[24][XS];
  __shared__ __align__(16) float x_s[Bz][XS];
  __shared__ __align__(16) float h_s[Bz][XS];
  __shared__ __align__(16) float at_s[Bz][516];
  __shared__ __align__(16) float e1_s[132];
  __shared__ __align__(16) float encpriv[Bz][Tz][4]; // own 4 dims of encout (8KB)
  __shared__ __align__(16) float hq_s[Bz][4];        // own 4 dims of h(s)
  __shared__ float sc_s[128];
  __shared__ float qh_s[128];
  __shared__ float g_s[Bz][6][4];
  __shared__ float sinv_s;
  __shared__ int ids_s[Bz];
  __shared__ u64 am_s[Bz][64];

  int epoch = 0;
  const int jbase = bid * 4;         // this block's 4 hidden dims
  const int t8 = tid >> 3, l8 = tid & 7;
  // GRU task map (t8<96), b-uniform per wave
  const int b8 = t8 / 24;
  const int r6 = t8 % 24;
  const int g6 = r6 >> 2, jl = r6 & 3;
  const int lrow = r6;
  const int grow = ((g6 < 3) ? g6 : g6 - 3) * Hz + jbase + jl;

  // ---- stage ENCODER GRU weights into LDS (once) ----
  for (int idx = tid; idx < 12 * Ez; idx += NTHR) {
    int lr = idx >> 9, c = idx & 511;
    wlds[lr][c] = enc_Wih[(long)((lr >> 2) * Hz + jbase + (lr & 3)) * Ez + c];
  }
  for (int idx = tid; idx < 12 * Hz; idx += NTHR) {
    int lr = idx >> 10, c = idx & 1023;
    wlds[12 + lr][c] = enc_Whh[(long)((lr >> 2) * Hz + jbase + (lr & 3)) * Hz + c];
  }
  float gbias = 0.f;
  if (t8 < 96) gbias = (g6 < 3) ? enc_bih[grow] : enc_bhh[grow];
  __syncthreads();

  // ================= encoder: 128 GRU steps =================
  for (int t = 0; t < Tz; ++t) {
    float* hrd = h_g + (t & 1) * (Bz * Hz);
    float* hwr = h_g + ((t + 1) & 1) * (Bz * Hz);
    for (int idx = tid; idx < Bz * Ez; idx += NTHR) {
      int b = idx >> 9, k = idx & 511;
      x_s[b][k] = enc_emb[(long)inputs[b * Tz + t] * Ez + k];
    }
    for (int idx = tid; idx < Bz * Hz; idx += NTHR)
      h_s[idx >> 10][idx & 1023] = hrd[idx];
    __syncthreads();
    if (t8 < 96) {
      const float4* w4 = (const float4*)&wlds[lrow][0];
      float acc;
      if (g6 < 3) acc = idot<16, 8>(w4, (const float4*)&x_s[b8][0], l8);
      else        acc = idot<32, 8>(w4, (const float4*)&h_s[b8][0], l8);
      acc += __shfl_xor(acc, 1); acc += __shfl_xor(acc, 2); acc += __shfl_xor(acc, 4);
      if (l8 == 0) g_s[b8][g6][jl] = acc + gbias;
    }
    __syncthreads();
    if (tid < 16) {
      int b = tid & 3, jj = tid >> 2;
      int j = jbase + jj;
      float r = sigf(g_s[b][0][jj] + g_s[b][3][jj]);
      float z = sigf(g_s[b][1][jj] + g_s[b][4][jj]);
      float n = tanhf(g_s[b][2][jj] + r * g_s[b][5][jj]);
      float hv = (1.0f - z) * n + z * h_s[b][j];
      hwr[b * Hz + j] = hv;
      encout_g[((long)(b * Tz) + t) * Hz + j] = hv;
      encpriv[b][t][jj] = hv;   // private copy for decoder score partials
    }
    ++epoch; bar_arrive(ctrl, epoch); bar_wait(ctrl, epoch);
  }

  // ================= P_t = enc_outs @ W_av_ctx^T (one-time) =================
  {
    int a = (bid >> 2) * 8 + (tid >> 7);
    int bt = (bid & 3) * 128 + (tid & 127);
    int b = bt >> 7, t2 = bt & 127;
    float acc = idot<256, 1>((const float4*)(W_av + (long)a * (2 * Hz)),
                             (const float4*)(encout_g + (long)bt * Hz), 0);
    pt_g[((long)(b * Az) + a) * Tz + t2] = acc;
    ++epoch; bar_arrive(ctrl, epoch); bar_wait(ctrl, epoch);
  }

  // ---- swap LDS weights: encoder -> decoder GRU ----
  for (int idx = tid; idx < 12 * Hz; idx += NTHR) {
    int lr = idx >> 10, c = idx & 1023;
    long gr = (long)((lr >> 2) * Hz + jbase + (lr & 3));
    wlds[lr][c] = dec_Wih[gr * 1024 + c];
    wlds[12 + lr][c] = dec_Whh[gr * Hz + c];
  }
  if (t8 < 96) gbias = (g6 < 3) ? dec_bih[grow] : dec_bhh[grow];

  // ============ W_cls pinned in registers for the whole decoder ============
  const int task16 = tid >> 4, l16 = tid & 15;
  const int nrows = 62 + (bid < 128 ? 1 : 0);
  const int rbase = bid * 62 + (bid < 128 ? bid : 128);
  const int myrow = rbase + (task16 < nrows ? task16 : 0);
  float4 wreg[8];
  {
    const float4* wr4 = (const float4*)(W_cls + (long)myrow * Az);
#pragma unroll
    for (int k = 0; k < 8; ++k) wreg[k] = wr4[l16 + 16 * k];
  }
  const float bclsr = b_cls[myrow];

  const int atn_b = bid & 3;          // attn block: batch
  const int abase = (bid >> 2) * 128; // attn block: a-slice base
  __syncthreads();                    // wlds swap complete before first decoder step

  // ================= decoder: 512 greedy steps =================
  for (int s = 0; s < NSTEPS; ++s) {
    float* hrd = h_g + (s & 1) * (Bz * Hz);
    float* hwr = h_g + ((s & 1) ^ 1) * (Bz * Hz);

    // ---- P1: argmax finalize -> ids, stage x/h, GRU (all 256 blocks) ----
    if (tid < 256) {
      int b = tid >> 6, l = tid & 63;
      u64 best = 0;
#pragma unroll
      for (int g = 0; g < 4; ++g) {
        u64 v = amax_g[(l + 64 * g) * 4 + b];
        best = v > best ? v : best;
      }
      for (int off = 32; off; off >>= 1) {
        u64 o = __shfl_xor(best, off);
        best = o > best ? o : best;
      }
      if (l == 0) ids_s[b] = (int)(0xFFFFFFFFu - (u32)(best & 0xFFFFFFFFull));
    }
    __syncthreads();
    for (int idx = tid; idx < Bz * (Ez + Az); idx += NTHR) {
      int b = idx >> 10, k = idx & 1023;
      x_s[b][k] = (k < Ez) ? dec_emb[(long)ids_s[b] * Ez + k] : av_g[b * Az + (k - Ez)];
    }
    for (int idx = tid; idx < Bz * Hz; idx += NTHR)
      h_s[idx >> 10][idx & 1023] = hrd[idx];
    __syncthreads();
    if (t8 < 96) {
      const float4* w4 = (const float4*)&wlds[lrow][0];
      const float4* v4 = (const float4*)((g6 < 3) ? &x_s[b8][0] : &h_s[b8][0]);
      float acc = idot<32, 8>(w4, v4, l8);
      acc += __shfl_xor(acc, 1); acc += __shfl_xor(acc, 2); acc += __shfl_xor(acc, 4);
      if (l8 == 0) g_s[b8][g6][jl] = acc + gbias;
    }
    __syncthreads();
    if (tid < 16) {
      int b = tid & 3, jj = tid >> 2;
      int j = jbase + jj;
      float r = sigf(g_s[b][0][jj] + g_s[b][3][jj]);
      float z = sigf(g_s[b][1][jj] + g_s[b][4][jj]);
      float n = tanhf(g_s[b][2][jj] + r * g_s[b][5][jj]);
      float hv = (1.0f - z) * n + z * h_s[b][j];
      hwr[b * Hz + j] = hv;
      hq_s[b][jj] = hv;
    }
    __syncthreads();
    // ---- distributed score/qh partials (this block's 4 h-dims) ----
    if (tid < 512) {
      int b = tid >> 7, t = tid & 127;
      float4 e = *(const float4*)&encpriv[b][t][0];
      float4 hq = *(const float4*)&hq_s[b][0];
      scorepart_g[((long)(b * Tz) + t) * 256 + bid] =
          e.x * hq.x + e.y * hq.y + e.z * hq.z + e.w * hq.w;
    } else {
      int a = tid - 512;
      float4 w = *(const float4*)(W_av + (long)a * (2 * Hz) + Hz + jbase);
#pragma unroll
      for (int b = 0; b < 4; ++b) {
        float4 hq = *(const float4*)&hq_s[b][0];
        qhpart_g[((long)(b * Az) + a) * 256 + bid] =
            w.x * hq.x + w.y * hq.y + w.z * hq.z + w.w * hq.w;
      }
    }
    ++epoch;
    bar_arrive(ctrl, epoch);   // h+partials ready: everyone arrives...

    // ---- P2: reduce scores+qh, softmax, ctx, av — blocks 0..15 only ----
    if (bid < 16) {
      bar_wait(ctrl, epoch);   // ...only attn blocks poll
      const int b = atn_b;
      {
        const int t = tid >> 3;  // 128 tasks x 8 lanes: sum 256 score partials
        float acc = isum<8, 8>(scorepart_g + ((long)(b * Tz) + t) * 256, l8);
        acc += __shfl_xor(acc, 1); acc += __shfl_xor(acc, 2); acc += __shfl_xor(acc, 4);
        if (l8 == 0) sc_s[t] = (inputs[b * Tz + t] != 0) ? acc : -1e30f;
        const int a = tid >> 3;  // 128 tasks x 8 lanes: sum 256 qh partials
        float qa = isum<8, 8>(qhpart_g + ((long)(b * Az) + abase + a) * 256, l8);
        qa += __shfl_xor(qa, 1); qa += __shfl_xor(qa, 2); qa += __shfl_xor(qa, 4);
        if (l8 == 0) qh_s[a] = qa;
      }
      __syncthreads();
      if (tid < 64) {  // softmax over 128 in wave 0
        float s0 = sc_s[tid], s1 = sc_s[64 + tid];
        float m = fmaxf(s0, s1);
#pragma unroll
        for (int off = 32; off; off >>= 1) m = fmaxf(m, __shfl_xor(m, off));
        float e0 = expf(s0 - m), e1 = expf(s1 - m);
        float sum = e0 + e1;
#pragma unroll
        for (int off = 32; off; off >>= 1) sum += __shfl_xor(sum, off);
        e1_s[tid] = e0; e1_s[64 + tid] = e1;
        if (tid == 0) sinv_s = 1.0f / sum;
      }
      __syncthreads();
      {
        const int a = tid >> 3;  // 128 tasks x 8 lanes: context dot over t
        float ctx = idot<4, 8>((const float4*)(pt_g + ((long)(b * Az) + abase + a) * Tz),
                               (const float4*)e1_s, l8);
        ctx += __shfl_xor(ctx, 1); ctx += __shfl_xor(ctx, 2); ctx += __shfl_xor(ctx, 4);
        if (l8 == 0)
          av_g[b * Az + abase + a] = tanhf(ctx * sinv_s + qh_s[a] + b_av[abase + a]);
      }
      if (bid < 4 && tid < 128)  // slice-0 blocks also emit attention weights
        out_aw[(long)s * (Bz * Tz) + bid * Tz + tid] = e1_s[tid] * sinv_s;
      __syncthreads();  // drain av/aw stores before release
      if (tid == 0)
        __hip_atomic_fetch_add(ctrl + 384, 1u, __ATOMIC_RELEASE, __HIP_MEMORY_SCOPE_AGENT);
    }

    // ---- all blocks: wait for av ready (16 producers) ----
    if (tid == 0) {
      const u32 tgt = (u32)(16 * (s + 1));
      while (__hip_atomic_load(ctrl + 384, __ATOMIC_RELAXED, __HIP_MEMORY_SCOPE_AGENT) < tgt)
        __builtin_amdgcn_s_sleep(8);
      (void)__hip_atomic_load(ctrl + 384, __ATOMIC_ACQUIRE, __HIP_MEMORY_SCOPE_AGENT);
    }
    __syncthreads();

    // ---- P3: logits from register-resident W_cls + block-local argmax ----
    for (int idx = tid; idx < Bz * Az; idx += NTHR)
      at_s[idx >> 9][idx & 511] = av_g[idx];
    __syncthreads();
#pragma unroll
    for (int b = 0; b < 4; ++b) {
      const float4* a4 = (const float4*)&at_s[b][0];
      float acc = 0.f;
#pragma unroll
      for (int k = 0; k < 8; ++k) {
        float4 a = a4[l16 + 16 * k];
        acc += wreg[k].x * a.x + wreg[k].y * a.y + wreg[k].z * a.z + wreg[k].w * a.w;
      }
      acc += __shfl_xor(acc, 1); acc += __shfl_xor(acc, 2);
      acc += __shfl_xor(acc, 4); acc += __shfl_xor(acc, 8);
      if (l16 == 0 && task16 < nrows) {
        acc += bclsr;
        out_pred[((long)s * Bz + b) * Vz + myrow] = acc;
        u32 u = __float_as_uint(acc);
        u = (u & 0x80000000u) ? ~u : (u | 0x80000000u);
        am_s[b][task16] = ((u64)u << 32) | (u64)(0xFFFFFFFFu - (u32)myrow);
      }
    }
    __syncthreads();
    if (tid < 256) {
      int b2 = tid >> 6, l = tid & 63;
      u64 best = (l < nrows) ? am_s[b2][l] : 0ull;
      for (int off = 32; off; off >>= 1) {
        u64 o = __shfl_xor(best, off);
        best = o > best ? o : best;
      }
      if (l == 0) amax_g[bid * 4 + b2] = best;
    }
    ++epoch;
    bar_arrive(ctrl, epoch);  // step-end: full barrier (argmax partials)
    bar_wait(ctrl, epoch);
  }
}

extern "C" void kernel_launch(void* const* d_in, const int* in_sizes, int n_in,
                              void* d_out, int out_size, void* d_ws, size_t ws_size,
                              hipStream_t stream) {
  const int* inputs = (const int*)d_in[0];
  const float* enc_emb = (const float*)d_in[1];
  const float* enc_Wih = (const float*)d_in[2];
  const float* enc_Whh = (const float*)d_in[3];
  const float* enc_bih = (const float*)d_in[4];
  const float* enc_bhh = (const float*)d_in[5];
  const float* dec_emb = (const float*)d_in[6];
  const float* dec_Wih = (const float*)d_in[7];
  const float* dec_Whh = (const float*)d_in[8];
  const float* dec_bih = (const float*)d_in[9];
  const float* dec_bhh = (const float*)d_in[10];
  const float* W_av = (const float*)d_in[11];
  const float* b_av = (const float*)d_in[12];
  const float* W_cls = (const float*)d_in[13];
  const float* b_cls = (const float*)d_in[14];

  // zero barrier state + h (both buffers) + attn_vec; 0xFF argmax partials so
  // step-0 ids decode to 0
  hipMemsetAsync(d_ws, 0, 57344, stream);
  hipMemsetAsync((char*)d_ws + 57344, 0xFF, 8192, stream);

  seq2seq_kernel<<<dim3(NBLK), dim3(NTHR), 0, stream>>>(
      inputs, enc_emb, enc_Wih, enc_Whh, enc_bih, enc_bhh,
      dec_emb, dec_Wih, dec_Whh, dec_bih, dec_bhh,
      W_av, b_av, W_cls, b_cls,
      (float*)d_out, (char*)d_ws);
}

// Round 7
// 18640.913 us; speedup vs baseline: 1.3625x; 1.3625x over previous
//
#include <hip/hip_runtime.h>
#include <stdint.h>

typedef unsigned int u32;
typedef unsigned long long u64;

#define NBLK 256
#define NTHR 1024
#define Bz 4
#define Tz 128
#define Hz 1024
#define Ez 512
#define Az 512
#define Vz 16000
#define NSTEPS 512
#define XS 1032   // LDS row stride (floats); 1032*4 bytes is 16B-aligned, 8-bank shift/row

// ---------------- ws layout (bytes) ----------------
// [0,     2048)   classic-bar ctrl: grp[g]@g*64B (g<16), root@1024, gen@1280, avflag@1536
// [8192,  9216)   hseq[256] u32   (decoder: block publishes h(s) -> s+1)
// [9216,  10240)  amseq[256] u32  (decoder: block publishes amax(s) -> s+1)
// [10240, 10752)  qhseq[32] u32, stride 4 u32 (qh block q publishes -> s+1)
// [10752, 10816)  idsline: u32 gen; int ids[4]  (reducer publishes, one cacheline)
// [16384, 49152)  h_g[2][4][1024] f32  (double-buffered)
// [49152, 57344)  av_g[4][512] f32
// [57344, 65536)  amax_g[256][4] u64
// [65536, 73728)  qh_g[4][512] f32
// [73728, +2MB)   encout[4][128][1024] f32, then pt[4][512][128] f32 (1MB)

__device__ __forceinline__ float sigf(float x) { return 1.0f / (1.0f + expf(-x)); }

__device__ __forceinline__ u32 ld_rlx(const u32* p) {
  return __hip_atomic_load(p, __ATOMIC_RELAXED, __HIP_MEMORY_SCOPE_AGENT);
}
__device__ __forceinline__ void st_rel(u32* p, u32 v) {
  __hip_atomic_store(p, v, __ATOMIC_RELEASE, __HIP_MEMORY_SCOPE_AGENT);
}

// wave0 polls a 256-slot seq array until ALL >= tgt; one acquire; block barrier.
__device__ __forceinline__ void poll256(const u32* sq, u32 tgt) {
  if (threadIdx.x < 64) {
    const int l = threadIdx.x;
    while (true) {
      u32 m0 = ld_rlx(sq + l);
      u32 m1 = ld_rlx(sq + l + 64);
      u32 m2 = ld_rlx(sq + l + 128);
      u32 m3 = ld_rlx(sq + l + 192);
      u32 a = m0 < m1 ? m0 : m1;
      u32 b = m2 < m3 ? m2 : m3;
      u32 mn = a < b ? a : b;
      if (__all(mn >= tgt)) break;
      __builtin_amdgcn_s_sleep(2);
    }
    if (l == 0)
      (void)__hip_atomic_load(sq, __ATOMIC_ACQUIRE, __HIP_MEMORY_SCOPE_AGENT);
  }
  __syncthreads();
}

// interleaved k-split dot: lane owns float4 chunks {lane + L*k : k<K}
template <int K, int L>
__device__ __forceinline__ float idot(const float4* __restrict__ w4,
                                      const float4* __restrict__ v4, int lane) {
  float4 acc = make_float4(0.f, 0.f, 0.f, 0.f);
#pragma unroll 8
  for (int k = 0; k < K; ++k) {
    float4 a = w4[lane + L * k];
    float4 b = v4[lane + L * k];
    acc.x += a.x * b.x; acc.y += a.y * b.y; acc.z += a.z * b.z; acc.w += a.w * b.w;
  }
  return (acc.x + acc.y) + (acc.z + acc.w);
}

// classic two-level grid barrier — encoder + P_t only.
__device__ __forceinline__ void bar_arrive(u32* ctrl, int epoch) {
  __syncthreads();
  if (threadIdx.x == 0) {
    const u32 target = (u32)epoch * 16u;
    u32* grp = ctrl + ((blockIdx.x >> 4) * 16);
    u32 v = __hip_atomic_fetch_add(grp, 1u, __ATOMIC_RELEASE, __HIP_MEMORY_SCOPE_AGENT);
    if (v == target - 1u) {
      u32 r = __hip_atomic_fetch_add(ctrl + 256, 1u, __ATOMIC_ACQ_REL, __HIP_MEMORY_SCOPE_AGENT);
      if (r == target - 1u)
        __hip_atomic_store(ctrl + 320, (u32)epoch, __ATOMIC_RELEASE, __HIP_MEMORY_SCOPE_AGENT);
    }
  }
}

__device__ __forceinline__ void bar_wait(u32* ctrl, int epoch) {
  if (threadIdx.x == 0) {
    while (__hip_atomic_load(ctrl + 320, __ATOMIC_RELAXED, __HIP_MEMORY_SCOPE_AGENT) < (u32)epoch)
      __builtin_amdgcn_s_sleep(4);
    (void)__hip_atomic_load(ctrl + 320, __ATOMIC_ACQUIRE, __HIP_MEMORY_SCOPE_AGENT);
  }
  __syncthreads();
}

__global__ void __launch_bounds__(NTHR, 1) seq2seq_kernel(
    const int* __restrict__ inputs,
    const float* __restrict__ enc_emb, const float* __restrict__ enc_Wih,
    const float* __restrict__ enc_Whh, const float* __restrict__ enc_bih,
    const float* __restrict__ enc_bhh,
    const float* __restrict__ dec_emb, const float* __restrict__ dec_Wih,
    const float* __restrict__ dec_Whh, const float* __restrict__ dec_bih,
    const float* __restrict__ dec_bhh,
    const float* __restrict__ W_av, const float* __restrict__ b_av,
    const float* __restrict__ W_cls, const float* __restrict__ b_cls,
    float* __restrict__ out, char* __restrict__ ws) {
  const int tid = threadIdx.x;
  const int bid = blockIdx.x;

  u32* ctrl = (u32*)ws;
  u32* hseq = (u32*)(ws + 8192);    // [256]
  u32* amseq = (u32*)(ws + 9216);   // [256]
  u32* qhseq = (u32*)(ws + 10240);  // [32] stride 4
  u32* idsline = (u32*)(ws + 10752);// gen; ids[4]
  float* h_g = (float*)(ws + 16384);     // [2][4][1024]
  float* av_g = (float*)(ws + 49152);    // [4][512]
  u64* amax_g = (u64*)(ws + 57344);      // [256][4]
  float* qh_g = (float*)(ws + 65536);    // [4][512]
  float* encout_g = (float*)(ws + 73728);
  float* pt_g = encout_g + Bz * Tz * Hz;
  float* out_pred = out;                        // [512][4][16000]
  float* out_aw = out + (long)NSTEPS * Bz * Vz; // [512][4][128]

  // GRU weights LDS-resident: rows 0..11 = W_ih, 12..23 = W_hh. ~96.75 KB.
  __shared__ __align__(16) float wlds[24][XS];
  __shared__ __align__(16) float x_s[Bz][XS];
  __shared__ __align__(16) float h_s[Bz][XS];
  __shared__ __align__(16) float at_s[Bz][516];
  __shared__ __align__(16) float hb_s[XS];
  __shared__ __align__(16) float e1_s[132];
  __shared__ float sc_s[128];
  __shared__ float g_s[Bz][6][4];
  __shared__ float sinv_s;
  __shared__ int ids_s[Bz];
  __shared__ int idsred[Bz];
  __shared__ u64 am_s[Bz][64];

  int epoch = 0;
  const int jbase = bid * 4;         // this block's 4 hidden dims
  const int t8 = tid >> 3, l8 = tid & 7;
  // GRU task map (t8<96), b-uniform per wave
  const int b8 = t8 / 24;
  const int r6 = t8 % 24;
  const int g6 = r6 >> 2, jl = r6 & 3;
  const int lrow = r6;
  const int grow = ((g6 < 3) ? g6 : g6 - 3) * Hz + jbase + jl;

  // ---- stage ENCODER GRU weights into LDS (once) ----
  for (int idx = tid; idx < 12 * Ez; idx += NTHR) {
    int lr = idx >> 9, c = idx & 511;
    wlds[lr][c] = enc_Wih[(long)((lr >> 2) * Hz + jbase + (lr & 3)) * Ez + c];
  }
  for (int idx = tid; idx < 12 * Hz; idx += NTHR) {
    int lr = idx >> 10, c = idx & 1023;
    wlds[12 + lr][c] = enc_Whh[(long)((lr >> 2) * Hz + jbase + (lr & 3)) * Hz + c];
  }
  float gbias = 0.f;
  if (t8 < 96) gbias = (g6 < 3) ? enc_bih[grow] : enc_bhh[grow];
  __syncthreads();

  // ================= encoder: 128 GRU steps =================
  for (int t = 0; t < Tz; ++t) {
    float* hrd = h_g + (t & 1) * (Bz * Hz);
    float* hwr = h_g + ((t + 1) & 1) * (Bz * Hz);
    for (int idx = tid; idx < Bz * Ez; idx += NTHR) {
      int b = idx >> 9, k = idx & 511;
      x_s[b][k] = enc_emb[(long)inputs[b * Tz + t] * Ez + k];
    }
    for (int idx = tid; idx < Bz * Hz; idx += NTHR)
      h_s[idx >> 10][idx & 1023] = hrd[idx];
    __syncthreads();
    if (t8 < 96) {
      const float4* w4 = (const float4*)&wlds[lrow][0];
      float acc;
      if (g6 < 3) acc = idot<16, 8>(w4, (const float4*)&x_s[b8][0], l8);
      else        acc = idot<32, 8>(w4, (const float4*)&h_s[b8][0], l8);
      acc += __shfl_xor(acc, 1); acc += __shfl_xor(acc, 2); acc += __shfl_xor(acc, 4);
      if (l8 == 0) g_s[b8][g6][jl] = acc + gbias;
    }
    __syncthreads();
    if (tid < 16) {
      int b = tid & 3, jj = tid >> 2;
      int j = jbase + jj;
      float r = sigf(g_s[b][0][jj] + g_s[b][3][jj]);
      float z = sigf(g_s[b][1][jj] + g_s[b][4][jj]);
      float n = tanhf(g_s[b][2][jj] + r * g_s[b][5][jj]);
      float hv = (1.0f - z) * n + z * h_s[b][j];
      hwr[b * Hz + j] = hv;
      encout_g[((long)(b * Tz) + t) * Hz + j] = hv;
    }
    ++epoch; bar_arrive(ctrl, epoch); bar_wait(ctrl, epoch);
  }

  // ================= P_t = enc_outs @ W_av_ctx^T (one-time) =================
  {
    int a = (bid >> 2) * 8 + (tid >> 7);
    int bt = (bid & 3) * 128 + (tid & 127);
    int b = bt >> 7, t2 = bt & 127;
    float acc = idot<256, 1>((const float4*)(W_av + (long)a * (2 * Hz)),
                             (const float4*)(encout_g + (long)bt * Hz), 0);
    pt_g[((long)(b * Az) + a) * Tz + t2] = acc;
    ++epoch; bar_arrive(ctrl, epoch); bar_wait(ctrl, epoch);
  }

  // ---- swap LDS weights: encoder -> decoder GRU ----
  for (int idx = tid; idx < 12 * Hz; idx += NTHR) {
    int lr = idx >> 10, c = idx & 1023;
    long gr = (long)((lr >> 2) * Hz + jbase + (lr & 3));
    wlds[lr][c] = dec_Wih[gr * 1024 + c];
    wlds[12 + lr][c] = dec_Whh[gr * Hz + c];
  }
  if (t8 < 96) gbias = (g6 < 3) ? dec_bih[grow] : dec_bhh[grow];

  // ============ W_cls pinned in registers for the whole decoder ============
  const int task16 = tid >> 4, l16 = tid & 15;
  const int nrows = 62 + (bid < 128 ? 1 : 0);
  const int rbase = bid * 62 + (bid < 128 ? bid : 128);
  const int myrow = rbase + (task16 < nrows ? task16 : 0);
  float4 wreg[8];
  {
    const float4* wr4 = (const float4*)(W_cls + (long)myrow * Az);
#pragma unroll
    for (int k = 0; k < 8; ++k) wreg[k] = wr4[l16 + 16 * k];
  }
  const float bclsr = b_cls[myrow];

  // ---- decoder roles ----
  const bool is_atn = bid < 16;                 // fused scores/softmax/ctx/av
  const bool is_qh = (bid >= 16) && (bid < 48); // qh dot producers
  const bool is_red = bid == 48;                // argmax reducer
  const int atn_b = bid & 3;                    // attn: batch
  const int abase = (bid >> 2) * 128;           // attn: a-slice base
  const int qbase = (bid - 16) * 16;            // qh: a-range base
  __syncthreads();                    // wlds swap complete before first decoder step

  // ================= decoder: 512 greedy steps =================
  for (int s = 0; s < NSTEPS; ++s) {
    float* hrd = h_g + (s & 1) * (Bz * Hz);
    float* hwr = h_g + ((s & 1) ^ 1) * (Bz * Hz);

    // ---- P1: wait ids(s-1) from reducer (single line), stage, GRU ----
    if (tid == 0) {
      while (ld_rlx(idsline) < (u32)s) __builtin_amdgcn_s_sleep(2);
      (void)__hip_atomic_load(idsline, __ATOMIC_ACQUIRE, __HIP_MEMORY_SCOPE_AGENT);
      const int* idp = (const int*)(idsline + 1);
      ids_s[0] = idp[0]; ids_s[1] = idp[1]; ids_s[2] = idp[2]; ids_s[3] = idp[3];
    }
    __syncthreads();
    for (int idx = tid; idx < Bz * (Ez + Az); idx += NTHR) {
      int b = idx >> 10, k = idx & 1023;
      x_s[b][k] = (k < Ez) ? dec_emb[(long)ids_s[b] * Ez + k] : av_g[b * Az + (k - Ez)];
    }
    for (int idx = tid; idx < Bz * Hz; idx += NTHR)
      h_s[idx >> 10][idx & 1023] = hrd[idx];
    __syncthreads();
    if (t8 < 96) {
      const float4* w4 = (const float4*)&wlds[lrow][0];
      const float4* v4 = (const float4*)((g6 < 3) ? &x_s[b8][0] : &h_s[b8][0]);
      float acc = idot<32, 8>(w4, v4, l8);
      acc += __shfl_xor(acc, 1); acc += __shfl_xor(acc, 2); acc += __shfl_xor(acc, 4);
      if (l8 == 0) g_s[b8][g6][jl] = acc + gbias;
    }
    __syncthreads();
    if (tid < 16) {
      int b = tid & 3, jj = tid >> 2;
      int j = jbase + jj;
      float r = sigf(g_s[b][0][jj] + g_s[b][3][jj]);
      float z = sigf(g_s[b][1][jj] + g_s[b][4][jj]);
      float n = tanhf(g_s[b][2][jj] + r * g_s[b][5][jj]);
      hwr[b * Hz + j] = (1.0f - z) * n + z * h_s[b][j];
    }
    __syncthreads();
    if (tid == 0) st_rel(hseq + bid, (u32)(s + 1));   // h(s) published

    // ---- P2a: qh producers (blocks 16..47) ----
    if (is_qh) {
      poll256(hseq, (u32)(s + 1));
      for (int idx = tid; idx < Bz * Hz; idx += NTHR)
        x_s[idx >> 10][idx & 1023] = hwr[idx];      // reuse x_s for h(s)
      __syncthreads();
      {
        int al = task16 >> 2, b = task16 & 3;       // 64 tasks x 16 lanes
        int a = qbase + al;
        float qa = idot<16, 16>((const float4*)(W_av + (long)a * (2 * Hz) + Hz),
                                (const float4*)&x_s[b][0], l16);
        qa += __shfl_xor(qa, 1); qa += __shfl_xor(qa, 2);
        qa += __shfl_xor(qa, 4); qa += __shfl_xor(qa, 8);
        if (l16 == 0) qh_g[b * Az + a] = qa;
      }
      __syncthreads();
      if (tid == 0) st_rel(qhseq + (bid - 16) * 4, (u32)(s + 1));
    }

    // ---- P2b: attn blocks 0..15: scores+softmax, join qh, ctx+av ----
    if (is_atn) {
      poll256(hseq, (u32)(s + 1));
      const int b = atn_b;
      for (int idx = tid; idx < Hz; idx += NTHR) hb_s[idx] = hwr[b * Hz + idx];
      __syncthreads();
      {
        const int t = tid >> 3;  // 128 tasks x 8 lanes: score dot
        float acc = idot<32, 8>((const float4*)(encout_g + ((long)(b * Tz) + t) * Hz),
                                (const float4*)hb_s, l8);
        acc += __shfl_xor(acc, 1); acc += __shfl_xor(acc, 2); acc += __shfl_xor(acc, 4);
        if (l8 == 0) sc_s[t] = (inputs[b * Tz + t] != 0) ? acc : -1e30f;
      }
      __syncthreads();
      if (tid < 64) {  // softmax over 128 in wave 0
        float s0 = sc_s[tid], s1 = sc_s[64 + tid];
        float m = fmaxf(s0, s1);
#pragma unroll
        for (int off = 32; off; off >>= 1) m = fmaxf(m, __shfl_xor(m, off));
        float e0 = expf(s0 - m), e1 = expf(s1 - m);
        float sum = e0 + e1;
#pragma unroll
        for (int off = 32; off; off >>= 1) sum += __shfl_xor(sum, off);
        e1_s[tid] = e0; e1_s[64 + tid] = e1;
        if (tid == 0) sinv_s = 1.0f / sum;
      }
      __syncthreads();
      // join the 8 qh slots covering [abase, abase+128)
      if (tid < 64) {
        const int sb = (bid >> 2) * 8;
        while (true) {
          u32 v = (tid < 8) ? ld_rlx(qhseq + (sb + tid) * 4) : 0xFFFFFFFFu;
          if (__all(v >= (u32)(s + 1))) break;
          __builtin_amdgcn_s_sleep(2);
        }
        if (tid == 0)
          (void)__hip_atomic_load(qhseq, __ATOMIC_ACQUIRE, __HIP_MEMORY_SCOPE_AGENT);
      }
      __syncthreads();
      {
        const int a = tid >> 3;  // 128 tasks x 8 lanes: context dot over t
        float ctx = idot<4, 8>((const float4*)(pt_g + ((long)(b * Az) + abase + a) * Tz),
                               (const float4*)e1_s, l8);
        ctx += __shfl_xor(ctx, 1); ctx += __shfl_xor(ctx, 2); ctx += __shfl_xor(ctx, 4);
        if (l8 == 0)
          av_g[b * Az + abase + a] =
              tanhf(ctx * sinv_s + qh_g[b * Az + abase + a] + b_av[abase + a]);
      }
      if (bid < 4 && tid < 128)  // slice-0 blocks also emit attention weights
        out_aw[(long)s * (Bz * Tz) + bid * Tz + tid] = e1_s[tid] * sinv_s;
      __syncthreads();  // drain av/aw stores before release
      if (tid == 0)
        __hip_atomic_fetch_add(ctrl + 384, 1u, __ATOMIC_RELEASE, __HIP_MEMORY_SCOPE_AGENT);
    }

    // ---- all blocks: wait for av ready (16 producers, single line) ----
    if (tid == 0) {
      const u32 tgt = (u32)(16 * (s + 1));
      while (__hip_atomic_load(ctrl + 384, __ATOMIC_RELAXED, __HIP_MEMORY_SCOPE_AGENT) < tgt)
        __builtin_amdgcn_s_sleep(8);
      (void)__hip_atomic_load(ctrl + 384, __ATOMIC_ACQUIRE, __HIP_MEMORY_SCOPE_AGENT);
    }
    __syncthreads();

    // ---- P3: logits from register-resident W_cls + block-local argmax ----
    for (int idx = tid; idx < Bz * Az; idx += NTHR)
      at_s[idx >> 9][idx & 511] = av_g[idx];
    __syncthreads();
#pragma unroll
    for (int b = 0; b < 4; ++b) {
      const float4* a4 = (const float4*)&at_s[b][0];
      float acc = 0.f;
#pragma unroll
      for (int k = 0; k < 8; ++k) {
        float4 a = a4[l16 + 16 * k];
        acc += wreg[k].x * a.x + wreg[k].y * a.y + wreg[k].z * a.z + wreg[k].w * a.w;
      }
      acc += __shfl_xor(acc, 1); acc += __shfl_xor(acc, 2);
      acc += __shfl_xor(acc, 4); acc += __shfl_xor(acc, 8);
      if (l16 == 0 && task16 < nrows) {
        acc += bclsr;
        out_pred[((long)s * Bz + b) * Vz + myrow] = acc;
        u32 u = __float_as_uint(acc);
        u = (u & 0x80000000u) ? ~u : (u | 0x80000000u);
        am_s[b][task16] = ((u64)u << 32) | (u64)(0xFFFFFFFFu - (u32)myrow);
      }
    }
    __syncthreads();
    if (tid < 256) {
      int b2 = tid >> 6, l = tid & 63;
      u64 best = (l < nrows) ? am_s[b2][l] : 0ull;
      for (int off = 32; off; off >>= 1) {
        u64 o = __shfl_xor(best, off);
        best = o > best ? o : best;
      }
      if (l == 0) amax_g[bid * 4 + b2] = best;
    }
    __syncthreads();
    if (tid == 0) st_rel(amseq + bid, (u32)(s + 1));  // partials published

    // ---- reducer block: final argmax over 256 partials, publish ids ----
    if (is_red) {
      poll256(amseq, (u32)(s + 1));
      if (tid < 256) {
        int b = tid >> 6, l = tid & 63;
        u64 best = 0;
#pragma unroll
        for (int g = 0; g < 4; ++g) {
          u64 v = amax_g[(l + 64 * g) * 4 + b];
          best = v > best ? v : best;
        }
        for (int off = 32; off; off >>= 1) {
          u64 o = __shfl_xor(best, off);
          best = o > best ? o : best;
        }
        if (l == 0) idsred[b] = (int)(0xFFFFFFFFu - (u32)(best & 0xFFFFFFFFull));
      }
      __syncthreads();
      if (tid == 0) {
        int* idp = (int*)(idsline + 1);
        idp[0] = idsred[0]; idp[1] = idsred[1]; idp[2] = idsred[2]; idp[3] = idsred[3];
        st_rel(idsline, (u32)(s + 1));   // gen+ids in one cacheline
      }
    }
  }
}

extern "C" void kernel_launch(void* const* d_in, const int* in_sizes, int n_in,
                              void* d_out, int out_size, void* d_ws, size_t ws_size,
                              hipStream_t stream) {
  const int* inputs = (const int*)d_in[0];
  const float* enc_emb = (const float*)d_in[1];
  const float* enc_Wih = (const float*)d_in[2];
  const float* enc_Whh = (const float*)d_in[3];
  const float* enc_bih = (const float*)d_in[4];
  const float* enc_bhh = (const float*)d_in[5];
  const float* dec_emb = (const float*)d_in[6];
  const float* dec_Wih = (const float*)d_in[7];
  const float* dec_Whh = (const float*)d_in[8];
  const float* dec_bih = (const float*)d_in[9];
  const float* dec_bhh = (const float*)d_in[10];
  const float* W_av = (const float*)d_in[11];
  const float* b_av = (const float*)d_in[12];
  const float* W_cls = (const float*)d_in[13];
  const float* b_cls = (const float*)d_in[14];

  // zero ctrl + all seq arrays + idsline (gen=0, ids=0 => step-0 starts with
  // token 0) + h (both buffers) + av + amax + qh regions.
  hipMemsetAsync(d_ws, 0, 73728, stream);

  seq2seq_kernel<<<dim3(NBLK), dim3(NTHR), 0, stream>>>(
      inputs, enc_emb, enc_Wih, enc_Whh, enc_bih, enc_bhh,
      dec_emb, dec_Wih, dec_Whh, dec_bih, dec_bhh,
      W_av, b_av, W_cls, b_cls,
      (float*)d_out, (char*)d_ws);
}